// Round 3
// baseline (129.063 us; speedup 1.0000x reference)
//
#include <hip/hip_runtime.h>
#include <math.h>

// z:     [16, 64, 32, 32] f32 -> N = 16384 queries of dim 64
// emb_w: [16384, 64] f32
// out:   1048576 f32 (z_q bchw) + 1 f32 (loss)
#define NQ      16384
#define NE      16384
#define DIM     64
#define QB      128               // queries per block (each wave holds all 128)
#define CSPLIT  4                 // code splits across blockIdx.y
#define CPB     (NE / CSPLIT)     // 4096 codes per block
#define CPW     (CPB / 4)         // 1024 codes per wave
#define THREADS 256

typedef _Float16 half8 __attribute__((ext_vector_type(8)));
typedef float    f32x4 __attribute__((ext_vector_type(4)));
typedef unsigned int   uint32;
typedef unsigned short uint16;

// ---------------- ws layout (f32 words) ----------------
// norms @ 0        [16384]
// pval  @ 16384    [4*16384]
// pidx  @ 81920    [4*16384 u16 = 32768 words]
// lossp @ 114688   [64]
// zh1   @ 114752   [524288]   (-2*z hi, fp16 row-major [n][64])
// zh2   @ 639040   [524288]   (-2*z lo)
// eh1   @ 1163328  [524288]   (emb hi)
// eh2   @ 1687616  [524288]   (emb lo)   -> total 8.85 MB

// Fused prep: blocks [0,64) split emb rows to fp16 hi/lo + ||e||^2;
// blocks [64,128) gather z from bchw, scale by -2, split to fp16 hi/lo.
__global__ __launch_bounds__(THREADS)
void vq_prep(const float* __restrict__ z, const float* __restrict__ emb,
             _Float16* __restrict__ zh1, _Float16* __restrict__ zh2,
             _Float16* __restrict__ eh1, _Float16* __restrict__ eh2,
             float* __restrict__ norms) {
    if (blockIdx.x < 64) {
        int e = blockIdx.x * THREADS + threadIdx.x;
        const float4* row = reinterpret_cast<const float4*>(emb + (size_t)e * DIM);
        float s = 0.f;
#pragma unroll
        for (int i = 0; i < DIM / 4; ++i) {
            float4 v = row[i];
            s = fmaf(v.x, v.x, s); s = fmaf(v.y, v.y, s);
            s = fmaf(v.z, v.z, s); s = fmaf(v.w, v.w, s);
            union { _Float16 h[4]; uint2 u; } p1, p2;
            float f[4] = {v.x, v.y, v.z, v.w};
#pragma unroll
            for (int j = 0; j < 4; ++j) {
                _Float16 h1 = (_Float16)f[j];
                p1.h[j] = h1;
                p2.h[j] = (_Float16)(f[j] - (float)h1);
            }
            *reinterpret_cast<uint2*>(eh1 + (size_t)e * DIM + i * 4) = p1.u;
            *reinterpret_cast<uint2*>(eh2 + (size_t)e * DIM + i * 4) = p2.u;
        }
        norms[e] = s;
    } else {
        int n = (blockIdx.x - 64) * THREADS + threadIdx.x;
        const float* zp = z + (size_t)(n >> 10) * 65536 + (n & 1023);
#pragma unroll 8
        for (int c = 0; c < DIM; ++c) {
            float x = -2.f * zp[(size_t)c * 1024];     // coalesced across lanes
            _Float16 h1 = (_Float16)x;
            _Float16 h2 = (_Float16)(x - (float)h1);
            zh1[(size_t)n * DIM + c] = h1;
            zh2[(size_t)n * DIM + c] = h2;
        }
    }
}

// LDS-free fp16x2-split MFMA distance GEMM + fused argmin.
// Block = 4 waves; all waves hold the SAME 128 queries in registers (A frags);
// each wave scans its own 1024-code range straight from L2 (no staging, no
// barriers). score = ||e||^2 + (-2z).e via acc-init = norm + 6 MFMAs.
// Running per-lane (min, packed 6-bit tile idx); 16-lane shfl reduce; 4-wave
// LDS reduce; one (val, idx) partial per (code-quarter, query).
__global__ __launch_bounds__(THREADS, 2)
void vq_mfma(const _Float16* __restrict__ zh1, const _Float16* __restrict__ zh2,
             const _Float16* __restrict__ eh1, const _Float16* __restrict__ eh2,
             const float* __restrict__ norms,
             float* __restrict__ pval, uint16* __restrict__ pidx) {
    __shared__ float  redv[4][QB];
    __shared__ uint32 redi[4][QB];

    const int t    = threadIdx.x;
    const int lane = t & 63;
    const int wave = t >> 6;
    const int r15  = lane & 15, hk = lane >> 4;
    const int qbase  = blockIdx.x * QB;
    const int cwbase = blockIdx.y * CPB + wave * CPW;   // this wave's code range
    const int crow   = cwbase + r15;                     // per-lane code row

    // A fragments: row = query (lane&15 within 16-tile), k = kc*32 + hk*8
    half8 A1[8][2], A2[8][2];
#pragma unroll
    for (int mt = 0; mt < 8; ++mt)
#pragma unroll
        for (int kc = 0; kc < 2; ++kc) {
            size_t off = (size_t)(qbase + mt * 16 + r15) * DIM + kc * 32 + hk * 8;
            A1[mt][kc] = *reinterpret_cast<const half8*>(zh1 + off);
            A2[mt][kc] = *reinterpret_cast<const half8*>(zh2 + off);
        }

    float  mv[32];
    uint32 mpk[8];
#pragma unroll
    for (int r = 0; r < 32; ++r) mv[r] = INFINITY;
#pragma unroll
    for (int r = 0; r < 8; ++r) mpk[r] = 0u;

    // current B fragments (code row = crow + cc), 1-deep manual prefetch
    half8 cb1[2], cb2[2];
    float cn;
    {
        const _Float16* p1 = eh1 + (size_t)crow * DIM + hk * 8;
        const _Float16* p2 = eh2 + (size_t)crow * DIM + hk * 8;
        cb1[0] = *reinterpret_cast<const half8*>(p1);
        cb1[1] = *reinterpret_cast<const half8*>(p1 + 32);
        cb2[0] = *reinterpret_cast<const half8*>(p2);
        cb2[1] = *reinterpret_cast<const half8*>(p2 + 32);
        cn = norms[crow];
    }

#pragma unroll 2
    for (int cc = 0; cc < CPW; cc += 16) {
        // prefetch next 16 code rows (clamped reload on last iter)
        int cnx = (cc + 16 < CPW) ? cc + 16 : cc;
        half8 nb1[2], nb2[2];
        float nn;
        {
            const _Float16* p1 = eh1 + (size_t)(crow + cnx) * DIM + hk * 8;
            const _Float16* p2 = eh2 + (size_t)(crow + cnx) * DIM + hk * 8;
            nb1[0] = *reinterpret_cast<const half8*>(p1);
            nb1[1] = *reinterpret_cast<const half8*>(p1 + 32);
            nb2[0] = *reinterpret_cast<const half8*>(p2);
            nb2[1] = *reinterpret_cast<const half8*>(p2 + 32);
            nn = norms[crow + cnx];
        }

        const uint32 cby = (uint32)(cc >> 4);   // 6-bit tile counter
#pragma unroll
        for (int mt = 0; mt < 8; ++mt) {
            f32x4 acc = {cn, cn, cn, cn};       // fold ||e||^2 into C-init
            __builtin_amdgcn_s_setprio(1);
            acc = __builtin_amdgcn_mfma_f32_16x16x32_f16(A1[mt][0], cb1[0], acc, 0, 0, 0);
            acc = __builtin_amdgcn_mfma_f32_16x16x32_f16(A1[mt][1], cb1[1], acc, 0, 0, 0);
            acc = __builtin_amdgcn_mfma_f32_16x16x32_f16(A1[mt][0], cb2[0], acc, 0, 0, 0);
            acc = __builtin_amdgcn_mfma_f32_16x16x32_f16(A1[mt][1], cb2[1], acc, 0, 0, 0);
            acc = __builtin_amdgcn_mfma_f32_16x16x32_f16(A2[mt][0], cb1[0], acc, 0, 0, 0);
            acc = __builtin_amdgcn_mfma_f32_16x16x32_f16(A2[mt][1], cb1[1], acc, 0, 0, 0);
            __builtin_amdgcn_s_setprio(0);
#pragma unroll
            for (int i = 0; i < 4; ++i) {
                const int r = mt * 4 + i;
                const uint32 sh = (uint32)((r & 3) * 8);
                bool lt = acc[i] < mv[r];                       // first-min: strict <
                uint32 ins = (mpk[r >> 2] & ~(0xFFu << sh)) | (cby << sh);
                mv[r]      = lt ? acc[i] : mv[r];
                mpk[r >> 2] = lt ? ins : mpk[r >> 2];
            }
        }
        cb1[0] = nb1[0]; cb1[1] = nb1[1];
        cb2[0] = nb2[0]; cb2[1] = nb2[1];
        cn = nn;
    }

    // reconstruct code indices, then 16-lane (code-column) reduce with
    // lower-index tiebreak (matches jnp.argmin first-min).
    uint32 ri[32];
#pragma unroll
    for (int r = 0; r < 32; ++r)
        ri[r] = (uint32)(cwbase + (int)(((mpk[r >> 2] >> ((r & 3) * 8)) & 0xFFu) << 4) + r15);
#pragma unroll
    for (int st = 1; st < 16; st <<= 1) {
#pragma unroll
        for (int r = 0; r < 32; ++r) {
            float  ov = __shfl_xor(mv[r], st, 64);
            uint32 oi = (uint32)__shfl_xor((int)ri[r], st, 64);
            if (ov < mv[r] || (ov == mv[r] && oi < ri[r])) { mv[r] = ov; ri[r] = oi; }
        }
    }
    if (r15 == 0) {
#pragma unroll
        for (int mt = 0; mt < 8; ++mt)
#pragma unroll
            for (int i = 0; i < 4; ++i) {
                int ql = mt * 16 + hk * 4 + i;      // C/D row mapping
                redv[wave][ql] = mv[mt * 4 + i];
                redi[wave][ql] = ri[mt * 4 + i];
            }
    }
    __syncthreads();

    // cross-wave reduce (ascending wave = ascending code range, strict <)
    if (t < QB) {
        float  bv = redv[0][t];
        uint32 bi = redi[0][t];
#pragma unroll
        for (int w = 1; w < 4; ++w) {
            float v = redv[w][t];
            if (v < bv) { bv = v; bi = redi[w][t]; }
        }
        pval[(size_t)blockIdx.y * NQ + qbase + t] = bv;
        pidx[(size_t)blockIdx.y * NQ + qbase + t] = (uint16)bi;
    }
}

// Reduce the CSPLIT partials per query (ascending split -> first-min), gather
// winning emb row, write bchw output, per-block deterministic loss partial.
__global__ __launch_bounds__(THREADS)
void vq_finalize(const float* __restrict__ z,
                 const float* __restrict__ emb,
                 const float* __restrict__ pval,
                 const uint16* __restrict__ pidx,
                 float* __restrict__ out,
                 float* __restrict__ lossp) {
    const int t = threadIdx.x;
    const int n = blockIdx.x * THREADS + t;

    float best = INFINITY;
    uint32 bi = 0u;
#pragma unroll
    for (int s = 0; s < CSPLIT; ++s) {
        float v = pval[(size_t)s * NQ + n];
        uint32 ix = (uint32)pidx[(size_t)s * NQ + n];
        if (v < best) { best = v; bi = ix; }
    }

    const float4* er = reinterpret_cast<const float4*>(emb + (size_t)bi * DIM);
    const float* zp = z   + (size_t)(n >> 10) * 65536 + (n & 1023);
    float*       op = out + (size_t)(n >> 10) * 65536 + (n & 1023);

    float ls = 0.f;
#pragma unroll
    for (int c4 = 0; c4 < DIM / 4; ++c4) {
        float4 e4 = er[c4];
        float zv, d;
        zv = zp[(c4 * 4 + 0) * 1024]; op[(c4 * 4 + 0) * 1024] = e4.x; d = e4.x - zv; ls = fmaf(d, d, ls);
        zv = zp[(c4 * 4 + 1) * 1024]; op[(c4 * 4 + 1) * 1024] = e4.y; d = e4.y - zv; ls = fmaf(d, d, ls);
        zv = zp[(c4 * 4 + 2) * 1024]; op[(c4 * 4 + 2) * 1024] = e4.z; d = e4.z - zv; ls = fmaf(d, d, ls);
        zv = zp[(c4 * 4 + 3) * 1024]; op[(c4 * 4 + 3) * 1024] = e4.w; d = e4.w - zv; ls = fmaf(d, d, ls);
    }

#pragma unroll
    for (int off = 32; off > 0; off >>= 1) ls += __shfl_down(ls, off, 64);
    __shared__ float wsum[THREADS / 64];
    if ((t & 63) == 0) wsum[t >> 6] = ls;
    __syncthreads();
    if (t == 0) {
        float s = 0.f;
#pragma unroll
        for (int w = 0; w < THREADS / 64; ++w) s += wsum[w];
        lossp[blockIdx.x] = s;
    }
}

__global__ __launch_bounds__(64)
void vq_loss_final(const float* __restrict__ lossp, float* __restrict__ out) {
    float v = lossp[threadIdx.x];
#pragma unroll
    for (int off = 32; off > 0; off >>= 1) v += __shfl_down(v, off, 64);
    if (threadIdx.x == 0)
        out[1048576] = 0.25f * v / 1048576.0f;   // BETA * mean
}

extern "C" void kernel_launch(void* const* d_in, const int* in_sizes, int n_in,
                              void* d_out, int out_size, void* d_ws, size_t ws_size,
                              hipStream_t stream) {
    const float* z   = (const float*)d_in[0];
    const float* emb = (const float*)d_in[1];
    float* out = (float*)d_out;

    float* ws = (float*)d_ws;
    float*     norms = ws;
    float*     pval  = ws + 16384;
    uint16*    pidx  = (uint16*)(ws + 81920);
    float*     lossp = ws + 114688;
    _Float16*  zh1   = (_Float16*)(ws + 114752);
    _Float16*  zh2   = (_Float16*)(ws + 639040);
    _Float16*  eh1   = (_Float16*)(ws + 1163328);
    _Float16*  eh2   = (_Float16*)(ws + 1687616);

    vq_prep<<<128, THREADS, 0, stream>>>(z, emb, zh1, zh2, eh1, eh2, norms);

    dim3 grid(NQ / QB, CSPLIT);   // 128 x 4 = 512 blocks
    vq_mfma<<<grid, THREADS, 0, stream>>>(zh1, zh2, eh1, eh2, norms, pval, pidx);

    vq_finalize<<<NQ / THREADS, THREADS, 0, stream>>>(z, emb, pval, pidx, out, lossp);
    vq_loss_final<<<1, 64, 0, stream>>>(lossp, out);
}

// Round 4
// 118.066 us; speedup vs baseline: 1.0931x; 1.0931x over previous
//
#include <hip/hip_runtime.h>
#include <math.h>

// z:     [16, 64, 32, 32] f32 -> N = 16384 queries of dim 64
// emb_w: [16384, 64] f32
// out:   1048576 f32 (z_q bchw) + 1 f32 (loss)
#define NQ      16384
#define NE      16384
#define DIM     64
#define QB      128               // queries per block (each wave holds all 128 as B-frags)
#define CSPLIT  4                 // code splits across blockIdx.y
#define CPB     (NE / CSPLIT)     // 4096 codes per block
#define CPW     (CPB / 4)         // 1024 codes per wave
#define NTIL    (CPW / 16)        // 64 tiles of 16 codes
#define THREADS 256

typedef _Float16 half8 __attribute__((ext_vector_type(8)));
typedef float    f32x4 __attribute__((ext_vector_type(4)));
typedef unsigned int   uint32;
typedef unsigned short uint16;

// ---------------- ws layout (f32 words) ----------------
// norms @ 0        [16384]
// pval  @ 16384    [4*16384]
// pgid  @ 81920    [4*16384 u16 = 32768 words]  (winning 4-code group id)
// lossp @ 114688   [64]
// zh1   @ 114752   [524288]   (z hi fp16, row-major [n][64])
// zh2   @ 639040   [524288]   (z lo)
// eh1   @ 1163328  [524288]   (-2*emb hi)
// eh2   @ 1687616  [524288]   (-2*emb lo)   -> total 8.85 MB
// NOTE: the -2 scale now lives on the CODE side (A operand); norms stay plain ||e||^2.

// Fused prep: blocks [0,64) split -2*emb rows to fp16 hi/lo + ||e||^2;
// blocks [64,128) gather z from bchw, split to fp16 hi/lo.
__global__ __launch_bounds__(THREADS)
void vq_prep(const float* __restrict__ z, const float* __restrict__ emb,
             _Float16* __restrict__ zh1, _Float16* __restrict__ zh2,
             _Float16* __restrict__ eh1, _Float16* __restrict__ eh2,
             float* __restrict__ norms) {
    if (blockIdx.x < 64) {
        int e = blockIdx.x * THREADS + threadIdx.x;
        const float4* row = reinterpret_cast<const float4*>(emb + (size_t)e * DIM);
        float s = 0.f;
#pragma unroll
        for (int i = 0; i < DIM / 4; ++i) {
            float4 v = row[i];
            s = fmaf(v.x, v.x, s); s = fmaf(v.y, v.y, s);
            s = fmaf(v.z, v.z, s); s = fmaf(v.w, v.w, s);
            union { _Float16 h[4]; uint2 u; } p1, p2;
            float f[4] = {-2.f * v.x, -2.f * v.y, -2.f * v.z, -2.f * v.w};
#pragma unroll
            for (int j = 0; j < 4; ++j) {
                _Float16 h1 = (_Float16)f[j];
                p1.h[j] = h1;
                p2.h[j] = (_Float16)(f[j] - (float)h1);
            }
            *reinterpret_cast<uint2*>(eh1 + (size_t)e * DIM + i * 4) = p1.u;
            *reinterpret_cast<uint2*>(eh2 + (size_t)e * DIM + i * 4) = p2.u;
        }
        norms[e] = s;
    } else {
        int n = (blockIdx.x - 64) * THREADS + threadIdx.x;
        const float* zp = z + (size_t)(n >> 10) * 65536 + (n & 1023);
#pragma unroll 8
        for (int c = 0; c < DIM; ++c) {
            float x = zp[(size_t)c * 1024];     // coalesced across lanes
            _Float16 h1 = (_Float16)x;
            _Float16 h2 = (_Float16)(x - (float)h1);
            zh1[(size_t)n * DIM + c] = h1;
            zh2[(size_t)n * DIM + c] = h2;
        }
    }
}

// LDS-free fp16x2-split MFMA + fused argmin, codes-as-A orientation:
// C/D row (hk*4+i) = code, col (lane&15) = query -> each lane's 4 acc elems are
// 4 codes of ONE query: collapse with min3+min, track (value, tile-id) only.
// ||e||^2 rides in as the first MFMA's C operand. Index recovered later from
// the 4-code group id = (tile, hk).
__global__ __launch_bounds__(THREADS, 2)
void vq_mfma(const _Float16* __restrict__ zh1, const _Float16* __restrict__ zh2,
             const _Float16* __restrict__ eh1, const _Float16* __restrict__ eh2,
             const float* __restrict__ norms,
             float* __restrict__ pval, uint16* __restrict__ pgid) {
    __shared__ float  redv[4][QB];
    __shared__ uint32 redg[4][QB];

    const int t    = threadIdx.x;
    const int lane = t & 63;
    const int wave = t >> 6;
    const int r15  = lane & 15, hk = lane >> 4;
    const int qbase  = blockIdx.x * QB;
    const int cwbase = blockIdx.y * CPB + wave * CPW;   // this wave's code range

    // B fragments (queries): col = r15, k = kc*32 + hk*8
    half8 B1[8][2], B2[8][2];
#pragma unroll
    for (int qt = 0; qt < 8; ++qt)
#pragma unroll
        for (int kc = 0; kc < 2; ++kc) {
            size_t off = (size_t)(qbase + qt * 16 + r15) * DIM + kc * 32 + hk * 8;
            B1[qt][kc] = *reinterpret_cast<const half8*>(zh1 + off);
            B2[qt][kc] = *reinterpret_cast<const half8*>(zh2 + off);
        }

    float  mv[8];
    uint32 mi[8];
#pragma unroll
    for (int q = 0; q < 8; ++q) { mv[q] = INFINITY; mi[q] = 0u; }

    // A fragments (codes, -2*emb): row = r15, k = kc*32 + hk*8; 1-deep prefetch
    half8 a1[2], a2[2];
    f32x4 nc;
    {
        const _Float16* p1 = eh1 + (size_t)(cwbase + r15) * DIM + hk * 8;
        const _Float16* p2 = eh2 + (size_t)(cwbase + r15) * DIM + hk * 8;
        a1[0] = *reinterpret_cast<const half8*>(p1);
        a1[1] = *reinterpret_cast<const half8*>(p1 + 32);
        a2[0] = *reinterpret_cast<const half8*>(p2);
        a2[1] = *reinterpret_cast<const half8*>(p2 + 32);
        nc = *reinterpret_cast<const f32x4*>(norms + cwbase + hk * 4);
    }

#pragma unroll 2
    for (int tile = 0; tile < NTIL; ++tile) {
        // prefetch next 16 code rows (clamped reload on last iter)
        int nt = (tile + 1 < NTIL) ? tile + 1 : tile;
        half8 b1[2], b2[2];
        f32x4 nn;
        {
            const _Float16* p1 = eh1 + (size_t)(cwbase + nt * 16 + r15) * DIM + hk * 8;
            const _Float16* p2 = eh2 + (size_t)(cwbase + nt * 16 + r15) * DIM + hk * 8;
            b1[0] = *reinterpret_cast<const half8*>(p1);
            b1[1] = *reinterpret_cast<const half8*>(p1 + 32);
            b2[0] = *reinterpret_cast<const half8*>(p2);
            b2[1] = *reinterpret_cast<const half8*>(p2 + 32);
            nn = *reinterpret_cast<const f32x4*>(norms + cwbase + nt * 16 + hk * 4);
        }

        const uint32 tid = (uint32)tile;
#pragma unroll
        for (int qt = 0; qt < 8; ++qt) {
            f32x4 acc;
            __builtin_amdgcn_s_setprio(1);
            acc = __builtin_amdgcn_mfma_f32_16x16x32_f16(a1[0], B1[qt][0], nc,  0, 0, 0);
            acc = __builtin_amdgcn_mfma_f32_16x16x32_f16(a1[1], B1[qt][1], acc, 0, 0, 0);
            acc = __builtin_amdgcn_mfma_f32_16x16x32_f16(a1[0], B2[qt][0], acc, 0, 0, 0);
            acc = __builtin_amdgcn_mfma_f32_16x16x32_f16(a1[1], B2[qt][1], acc, 0, 0, 0);
            acc = __builtin_amdgcn_mfma_f32_16x16x32_f16(a2[0], B1[qt][0], acc, 0, 0, 0);
            acc = __builtin_amdgcn_mfma_f32_16x16x32_f16(a2[1], B1[qt][1], acc, 0, 0, 0);
            __builtin_amdgcn_s_setprio(0);
            float m4 = fminf(fminf(fminf(acc[0], acc[1]), acc[2]), acc[3]);
            bool lt = m4 < mv[qt];                 // first-min: strict <
            mv[qt] = lt ? m4 : mv[qt];
            mi[qt] = lt ? tid : mi[qt];
        }
        a1[0] = b1[0]; a1[1] = b1[1];
        a2[0] = b2[0]; a2[1] = b2[1];
        nc = nn;
    }

    // group id = 4-code candidate group, globally ordered ascending in code idx
    uint32 gi[8];
#pragma unroll
    for (int q = 0; q < 8; ++q)
        gi[q] = (uint32)(cwbase >> 2) + (mi[q] << 2) + (uint32)hk;

    // reduce across hk groups (lanes r15, r15+16, r15+32, r15+48 share a query)
#pragma unroll
    for (int st = 16; st < 64; st <<= 1) {
#pragma unroll
        for (int q = 0; q < 8; ++q) {
            float  ov = __shfl_xor(mv[q], st, 64);
            uint32 og = (uint32)__shfl_xor((int)gi[q], st, 64);
            if (ov < mv[q] || (ov == mv[q] && og < gi[q])) { mv[q] = ov; gi[q] = og; }
        }
    }
    if (lane < 16) {
#pragma unroll
        for (int qt = 0; qt < 8; ++qt) {
            redv[wave][qt * 16 + lane] = mv[qt];
            redg[wave][qt * 16 + lane] = gi[qt];
        }
    }
    __syncthreads();

    // cross-wave reduce (ascending wave = ascending code range, strict <)
    if (t < QB) {
        float  bv = redv[0][t];
        uint32 bg = redg[0][t];
#pragma unroll
        for (int w = 1; w < 4; ++w) {
            float v = redv[w][t];
            if (v < bv) { bv = v; bg = redg[w][t]; }
        }
        pval[(size_t)blockIdx.y * NQ + qbase + t] = bv;
        pgid[(size_t)blockIdx.y * NQ + qbase + t] = (uint16)bg;
    }
}

// Per query: pick best (val,gid) over splits, re-evaluate the 4 candidate codes
// in fp32 (exact argmin among them, first-min), gather winning emb row, write
// bchw output, per-block deterministic loss partial.
__global__ __launch_bounds__(THREADS)
void vq_finalize(const float* __restrict__ z,
                 const float* __restrict__ emb,
                 const float* __restrict__ norms,
                 const float* __restrict__ pval,
                 const uint16* __restrict__ pgid,
                 float* __restrict__ out,
                 float* __restrict__ lossp) {
    const int t = threadIdx.x;
    const int n = blockIdx.x * THREADS + t;

    float best = INFINITY;
    uint32 bg = 0u;
#pragma unroll
    for (int s = 0; s < CSPLIT; ++s) {
        float v = pval[(size_t)s * NQ + n];
        uint32 g = (uint32)pgid[(size_t)s * NQ + n];
        if (v < best) { best = v; bg = g; }
    }

    // load the query in fp32 (coalesced across lanes: stride-1024 per channel)
    const float* zp = z + (size_t)(n >> 10) * 65536 + (n & 1023);
    float zq[DIM];
#pragma unroll
    for (int c = 0; c < DIM; ++c) zq[c] = zp[(size_t)c * 1024];

    // fp32 re-evaluation of the 4 candidates (score = ||e||^2 - 2 z.e)
    float4 nr = *reinterpret_cast<const float4*>(norms + bg * 4);
    float nra[4] = {nr.x, nr.y, nr.z, nr.w};
    float bs = INFINITY;
    uint32 bi = 0u;
#pragma unroll
    for (int j = 0; j < 4; ++j) {
        const float4* er = reinterpret_cast<const float4*>(emb + (size_t)(bg * 4 + j) * DIM);
        float dot = 0.f;
#pragma unroll
        for (int i = 0; i < DIM / 4; ++i) {
            float4 e4 = er[i];
            dot = fmaf(e4.x, zq[i * 4 + 0], dot);
            dot = fmaf(e4.y, zq[i * 4 + 1], dot);
            dot = fmaf(e4.z, zq[i * 4 + 2], dot);
            dot = fmaf(e4.w, zq[i * 4 + 3], dot);
        }
        float s = fmaf(-2.f, dot, nra[j]);
        if (s < bs) { bs = s; bi = bg * 4 + j; }   // ascending j = ascending code
    }

    const float4* ew = reinterpret_cast<const float4*>(emb + (size_t)bi * DIM);
    float* op = out + (size_t)(n >> 10) * 65536 + (n & 1023);

    float ls = 0.f;
#pragma unroll
    for (int c4 = 0; c4 < DIM / 4; ++c4) {
        float4 e4 = ew[c4];
        float d;
        op[(c4 * 4 + 0) * 1024] = e4.x; d = e4.x - zq[c4 * 4 + 0]; ls = fmaf(d, d, ls);
        op[(c4 * 4 + 1) * 1024] = e4.y; d = e4.y - zq[c4 * 4 + 1]; ls = fmaf(d, d, ls);
        op[(c4 * 4 + 2) * 1024] = e4.z; d = e4.z - zq[c4 * 4 + 2]; ls = fmaf(d, d, ls);
        op[(c4 * 4 + 3) * 1024] = e4.w; d = e4.w - zq[c4 * 4 + 3]; ls = fmaf(d, d, ls);
    }

#pragma unroll
    for (int off = 32; off > 0; off >>= 1) ls += __shfl_down(ls, off, 64);
    __shared__ float wsum[THREADS / 64];
    if ((t & 63) == 0) wsum[t >> 6] = ls;
    __syncthreads();
    if (t == 0) {
        float s = 0.f;
#pragma unroll
        for (int w = 0; w < THREADS / 64; ++w) s += wsum[w];
        lossp[blockIdx.x] = s;
    }
}

__global__ __launch_bounds__(64)
void vq_loss_final(const float* __restrict__ lossp, float* __restrict__ out) {
    float v = lossp[threadIdx.x];
#pragma unroll
    for (int off = 32; off > 0; off >>= 1) v += __shfl_down(v, off, 64);
    if (threadIdx.x == 0)
        out[1048576] = 0.25f * v / 1048576.0f;   // BETA * mean
}

extern "C" void kernel_launch(void* const* d_in, const int* in_sizes, int n_in,
                              void* d_out, int out_size, void* d_ws, size_t ws_size,
                              hipStream_t stream) {
    const float* z   = (const float*)d_in[0];
    const float* emb = (const float*)d_in[1];
    float* out = (float*)d_out;

    float* ws = (float*)d_ws;
    float*     norms = ws;
    float*     pval  = ws + 16384;
    uint16*    pgid  = (uint16*)(ws + 81920);
    float*     lossp = ws + 114688;
    _Float16*  zh1   = (_Float16*)(ws + 114752);
    _Float16*  zh2   = (_Float16*)(ws + 639040);
    _Float16*  eh1   = (_Float16*)(ws + 1163328);
    _Float16*  eh2   = (_Float16*)(ws + 1687616);

    vq_prep<<<128, THREADS, 0, stream>>>(z, emb, zh1, zh2, eh1, eh2, norms);

    dim3 grid(NQ / QB, CSPLIT);   // 128 x 4 = 512 blocks
    vq_mfma<<<grid, THREADS, 0, stream>>>(zh1, zh2, eh1, eh2, norms, pval, pgid);

    vq_finalize<<<NQ / THREADS, THREADS, 0, stream>>>(z, emb, norms, pval, pgid, out, lossp);
    vq_loss_final<<<1, 64, 0, stream>>>(lossp, out);
}